// Round 1
// baseline (148.113 us; speedup 1.0000x reference)
//
#include <hip/hip_runtime.h>
#include <hip/hip_bf16.h>
#include <stdint.h>

// ---------- helpers ----------
typedef __attribute__((ext_vector_type(8))) __bf16 bf16x8;
typedef __attribute__((ext_vector_type(4))) float f32x4;

__device__ inline float bf2f(unsigned short u) {
  union { unsigned u; float f; } z; z.u = ((unsigned)u) << 16; return z.f;
}
__device__ inline unsigned short f2bf(float f) {
  union { float f; unsigned u; } z; z.f = f;
  unsigned r = z.u + 0x7fffu + ((z.u >> 16) & 1u);
  return (unsigned short)(r >> 16);
}
__device__ inline void gload_lds16(const void* g, void* l) {
  __builtin_amdgcn_global_load_lds((const __attribute__((address_space(1))) void*)g,
                                   (__attribute__((address_space(3))) void*)l, 16, 0, 0);
}

// ---------- f32 -> bf16 convert ----------
__global__ __launch_bounds__(256) void cvt_bf16_kernel(const float* __restrict__ src,
                                                       unsigned short* __restrict__ dst) {
  long i = (long)blockIdx.x * 256 + threadIdx.x;
  const float4 v = *(const float4*)(src + i * 4);
  ushort4 o;
  o.x = f2bf(v.x); o.y = f2bf(v.y); o.z = f2bf(v.z); o.w = f2bf(v.w);
  *(ushort4*)(dst + i * 4) = o;
}

// ---------- bf16 NT GEMM: out[m][o] = sum_k A[m][k]*W[o][k] + bias[o] (+res) ----------
// EPI: 0 = f32 out, 1 = bf16 out, 2 = relu+bf16 out, 3 = +res, f32 out
template <int EPI>
__global__ __launch_bounds__(256, 2) void gemm_bt(
    const unsigned short* __restrict__ A,   // M x K (bf16 bits)
    const unsigned short* __restrict__ W,   // O x K (bf16 bits)
    const float* __restrict__ bias,         // O
    const float* __restrict__ res,          // M x O (EPI==3) or null
    float* __restrict__ outf,               // EPI 0/3
    unsigned short* __restrict__ outb,      // EPI 1/2
    int K, int O) {
  __shared__ __attribute__((aligned(16))) char lds[16384];  // A tile 8KB | B tile 8KB
  const int tid = threadIdx.x;
  const int lane = tid & 63;
  const int wm = (tid >> 6) >> 1, wo = (tid >> 6) & 1;
  const long bm = blockIdx.x, bo = blockIdx.y;

  f32x4 acc[4][4] = {};
  const int nk = K >> 5;
  const long rowbytes = (long)K * 2;
  const char* Ab = (const char*)(A + bm * 128 * (long)K);
  const char* Wb = (const char*)(W + bo * 128 * (long)K);

  for (int kt = 0; kt < nk; ++kt) {
#pragma unroll
    for (int c = 0; c < 2; ++c) {
      const int fb = tid * 16 + c * 4096;
      const int row = fb >> 6, colb = fb & 63;
      gload_lds16(Ab + row * rowbytes + kt * 64 + colb, lds + fb);
      gload_lds16(Wb + row * rowbytes + kt * 64 + colb, lds + 8192 + fb);
    }
    __syncthreads();
    bf16x8 af[4], bfr[4];
    const int kb_off = (lane >> 4) * 16;
#pragma unroll
    for (int i = 0; i < 4; ++i) {
      const int ra = wm * 64 + i * 16 + (lane & 15);
      af[i] = *(const bf16x8*)(lds + ra * 64 + kb_off);
      const int rb = wo * 64 + i * 16 + (lane & 15);
      bfr[i] = *(const bf16x8*)(lds + 8192 + rb * 64 + kb_off);
    }
#pragma unroll
    for (int i = 0; i < 4; ++i)
#pragma unroll
      for (int j = 0; j < 4; ++j)
        acc[i][j] = __builtin_amdgcn_mfma_f32_16x16x32_bf16(af[i], bfr[j], acc[i][j], 0, 0, 0);
    __syncthreads();
  }

#pragma unroll
  for (int i = 0; i < 4; ++i) {
#pragma unroll
    for (int j = 0; j < 4; ++j) {
      const int colg = (int)bo * 128 + wo * 64 + j * 16 + (lane & 15);
      const float bv = bias[colg];
#pragma unroll
      for (int r = 0; r < 4; ++r) {
        const long rowg = bm * 128 + wm * 64 + i * 16 + (lane >> 4) * 4 + r;
        float v = acc[i][j][r] + bv;
        if (EPI == 3) v += res[rowg * O + colg];
        if (EPI == 0 || EPI == 3) outf[rowg * O + colg] = v;
        else if (EPI == 1) outb[rowg * O + colg] = f2bf(v);
        else if (EPI == 2) outb[rowg * O + colg] = f2bf(v > 0.f ? v : 0.f);
      }
    }
  }
}

// ---------- fused gather + RPE rotary + MHA (one block per query) ----------
__global__ __launch_bounds__(256, 2) void attn_kernel(
    const float* __restrict__ qf,            // N x 256 (f32)
    const unsigned short* __restrict__ kbp,  // M x 256 (bf16)
    const unsigned short* __restrict__ vbp,  // M x 256 (bf16)
    const int* __restrict__ idx,             // N x 32
    const float* __restrict__ icoord,        // N x 3
    const float* __restrict__ mcoord,        // M x 3
    const float* __restrict__ mask,          // N x 32
    const float* __restrict__ Wrpe,          // 128 x 3
    const float* __restrict__ brpe,          // 128
    unsigned short* __restrict__ hb)         // N x 256 (bf16)
{
  __shared__ float q_s[256];
  __shared__ int idx_s[32];
  __shared__ float rel_s[32][3];
  __shared__ float mask_s[32];
  __shared__ __attribute__((aligned(16))) unsigned short kls[32][256];
  __shared__ __attribute__((aligned(16))) unsigned short vls[32][256];
  __shared__ float s_lds[256];
  __shared__ float p_lds[256];

  const int n = blockIdx.x, t = threadIdx.x;
  q_s[t] = qf[(long)n * 256 + t] * 0.17677669529663687f;  // 1/sqrt(32)
  if (t < 32) { idx_s[t] = idx[n * 32 + t]; mask_s[t] = mask[n * 32 + t]; }
  __syncthreads();

  if (t < 96) {
    const int r = t / 3, d = t % 3;
    rel_s[r][d] = mcoord[(long)idx_s[r] * 3 + d] - icoord[(long)n * 3 + d];
  }
  {
    const int r0 = t >> 5, c16 = (t & 31) * 16;
#pragma unroll
    for (int it = 0; it < 4; ++it) {
      const int r = it * 8 + r0;
      const long m = idx_s[r];
      gload_lds16((const char*)(kbp + m * 256) + c16, (char*)kls + r * 512 + c16);
      gload_lds16((const char*)(vbp + m * 256) + c16, (char*)vls + r * 512 + c16);
    }
  }
  __syncthreads();

  // rotary on gathered K (each thread owns one j-column across 16 k-rows)
  {
    const int j = t & 127, kh = (t >> 7) * 16;
    const float w0 = Wrpe[j * 3], w1 = Wrpe[j * 3 + 1], w2 = Wrpe[j * 3 + 2], bj = brpe[j];
    for (int k = kh; k < kh + 16; ++k) {
      const float ang = fmaf(w0, rel_s[k][0], fmaf(w1, rel_s[k][1], fmaf(w2, rel_s[k][2], bj)));
      const float sn = __sinf(ang), cs = __cosf(ang);
      const float x0 = bf2f(kls[k][2 * j]), x1 = bf2f(kls[k][2 * j + 1]);
      kls[k][2 * j] = f2bf(x0 * cs - x1 * sn);
      kls[k][2 * j + 1] = f2bf(x0 * sn + x1 * cs);
    }
  }
  __syncthreads();

  // scores: thread t -> (k = t>>3, h = t&7); lane-rotated reads avoid conflicts
  const int kk = t >> 3, h = t & 7;
  float sc = 0.f;
  {
    const int base = h * 32;
    for (int c = 0; c < 32; ++c) {
      const int cc = (c + t) & 31;
      sc = fmaf(q_s[base + cc], bf2f(kls[kk][base + cc]), sc);
    }
    sc -= 1e6f * (1.f - mask_s[kk]);
    s_lds[h * 32 + kk] = sc;
  }
  __syncthreads();

  float mx = -1e30f;
  for (int c = 0; c < 32; ++c) { const int cc = (c + t) & 31; mx = fmaxf(mx, s_lds[h * 32 + cc]); }
  float sum = 0.f;
  for (int c = 0; c < 32; ++c) { const int cc = (c + t) & 31; sum += __expf(s_lds[h * 32 + cc] - mx); }
  p_lds[kk * 8 + h] = __expf(sc - mx) / sum;
  __syncthreads();

  // PV: thread t = output channel
  {
    const int h2 = t >> 5;
    float acc = 0.f;
    for (int k = 0; k < 32; ++k)
      acc = fmaf(p_lds[k * 8 + h2], bf2f(vls[k][t]), acc);
    hb[(long)n * 256 + t] = f2bf(acc);
  }
}

// ---------- row LayerNorm over C=256 (wave per row, 4 rows/block) ----------
template <int WRITE_B>
__global__ __launch_bounds__(256) void ln_kernel(
    const float* __restrict__ in, const float* __restrict__ g, const float* __restrict__ b,
    float* __restrict__ outf, unsigned short* __restrict__ outb) {
  const long row = (long)blockIdx.x * 4 + (threadIdx.x >> 6);
  const int lane = threadIdx.x & 63;
  const float4 x = *(const float4*)(in + row * 256 + lane * 4);
  float s = x.x + x.y + x.z + x.w;
  float s2 = fmaf(x.x, x.x, fmaf(x.y, x.y, fmaf(x.z, x.z, x.w * x.w)));
#pragma unroll
  for (int o = 32; o > 0; o >>= 1) { s += __shfl_xor(s, o, 64); s2 += __shfl_xor(s2, o, 64); }
  const float mu = s * (1.f / 256.f);
  const float var = s2 * (1.f / 256.f) - mu * mu;
  const float inv = rsqrtf(var + 1e-5f);
  const float4 gv = *(const float4*)(g + lane * 4);
  const float4 bv = *(const float4*)(b + lane * 4);
  float4 y;
  y.x = (x.x - mu) * inv * gv.x + bv.x;
  y.y = (x.y - mu) * inv * gv.y + bv.y;
  y.z = (x.z - mu) * inv * gv.z + bv.z;
  y.w = (x.w - mu) * inv * gv.w + bv.w;
  *(float4*)(outf + row * 256 + lane * 4) = y;
  if (WRITE_B) {
    ushort4 yb;
    yb.x = f2bf(y.x); yb.y = f2bf(y.y); yb.z = f2bf(y.z); yb.w = f2bf(y.w);
    *(ushort4*)(outb + row * 256 + lane * 4) = yb;
  }
}

// ---------- launch ----------
extern "C" void kernel_launch(void* const* d_in, const int* in_sizes, int n_in,
                              void* d_out, int out_size, void* d_ws, size_t ws_size,
                              hipStream_t stream) {
  const float* x    = (const float*)d_in[0];
  const float* mem  = (const float*)d_in[1];
  const int* idx    = (const int*)d_in[2];
  const float* ic   = (const float*)d_in[3];
  const float* mc   = (const float*)d_in[4];
  const float* mask = (const float*)d_in[5];
  const float* Wq = (const float*)d_in[6];  const float* bq = (const float*)d_in[7];
  const float* Wk = (const float*)d_in[8];  const float* bk = (const float*)d_in[9];
  const float* Wv = (const float*)d_in[10]; const float* bv = (const float*)d_in[11];
  const float* Wo = (const float*)d_in[12]; const float* bo = (const float*)d_in[13];
  const float* g1 = (const float*)d_in[14]; const float* b1 = (const float*)d_in[15];
  const float* Wrpe = (const float*)d_in[16]; const float* brpe = (const float*)d_in[17];
  const float* We = (const float*)d_in[18]; const float* be = (const float*)d_in[19];
  const float* Ws = (const float*)d_in[20]; const float* bs = (const float*)d_in[21];
  const float* g2 = (const float*)d_in[22]; const float* b2 = (const float*)d_in[23];

  char* w = (char*)d_ws;
  const size_t MB = 1ull << 20;
  unsigned short* xb    = (unsigned short*)(w + 0);        // 4MB
  unsigned short* mb    = (unsigned short*)(w + 4 * MB);   // 4MB
  unsigned short* kbp   = (unsigned short*)(w + 8 * MB);   // 4MB
  unsigned short* vbp   = (unsigned short*)(w + 12 * MB);  // 4MB
  float*          qf    = (float*)(w + 16 * MB);           // 8MB
  unsigned short* hb    = (unsigned short*)(w + 24 * MB);  // 4MB
  float*          out1  = (float*)(w + 28 * MB);           // 8MB
  unsigned short* out1b = (unsigned short*)(w + 36 * MB);  // 4MB
  float*          t1    = (float*)(w + 16 * MB);           // reuse qf (dead after attn)
  unsigned short* ffb   = (unsigned short*)(w + 8 * MB);   // reuse k/v (dead after attn), 8MB
  float*          t2    = (float*)(w + 0);                 // reuse xb/mb (dead after projections)
  unsigned short* wqb = (unsigned short*)(w + 40 * MB);
  unsigned short* wkb = wqb + 65536;
  unsigned short* wvb = wkb + 65536;
  unsigned short* wob = wvb + 65536;
  unsigned short* web = wob + 65536;   // 512x256
  unsigned short* wsb = web + 131072;  // 256x512

  // converts to bf16
  cvt_bf16_kernel<<<2048, 256, 0, stream>>>(x, xb);
  cvt_bf16_kernel<<<2048, 256, 0, stream>>>(mem, mb);
  cvt_bf16_kernel<<<64, 256, 0, stream>>>(Wq, wqb);
  cvt_bf16_kernel<<<64, 256, 0, stream>>>(Wk, wkb);
  cvt_bf16_kernel<<<64, 256, 0, stream>>>(Wv, wvb);
  cvt_bf16_kernel<<<64, 256, 0, stream>>>(Wo, wob);
  cvt_bf16_kernel<<<128, 256, 0, stream>>>(We, web);
  cvt_bf16_kernel<<<128, 256, 0, stream>>>(Ws, wsb);

  // projections
  gemm_bt<0><<<dim3(64, 2), 256, 0, stream>>>(xb, wqb, bq, nullptr, qf, nullptr, 256, 256);
  gemm_bt<1><<<dim3(64, 2), 256, 0, stream>>>(mb, wkb, bk, nullptr, nullptr, kbp, 256, 256);
  gemm_bt<1><<<dim3(64, 2), 256, 0, stream>>>(mb, wvb, bv, nullptr, nullptr, vbp, 256, 256);

  // fused gather + rotary + attention
  attn_kernel<<<8192, 256, 0, stream>>>(qf, kbp, vbp, idx, ic, mc, mask, Wrpe, brpe, hb);

  // output proj + residual, LN1
  gemm_bt<3><<<dim3(64, 2), 256, 0, stream>>>(hb, wob, bo, x, t1, nullptr, 256, 256);
  ln_kernel<1><<<2048, 256, 0, stream>>>(t1, g1, b1, out1, out1b);

  // FFN
  gemm_bt<2><<<dim3(64, 4), 256, 0, stream>>>(out1b, web, be, nullptr, nullptr, ffb, 256, 512);
  gemm_bt<3><<<dim3(64, 2), 256, 0, stream>>>(ffb, wsb, bs, out1, t2, nullptr, 512, 256);
  ln_kernel<0><<<2048, 256, 0, stream>>>(t2, g2, b2, (float*)d_out, nullptr);
}

// Round 3
// 107.381 us; speedup vs baseline: 1.3793x; 1.3793x over previous
//
#include <hip/hip_runtime.h>
#include <hip/hip_bf16.h>
#include <stdint.h>

// ---------- helpers ----------
typedef __attribute__((ext_vector_type(8))) __bf16 bf16x8;
typedef __attribute__((ext_vector_type(8))) unsigned short u16x8;
typedef __attribute__((ext_vector_type(4))) float f32x4;

__device__ inline float bf2f(unsigned short u) {
  union { unsigned u; float f; } z; z.u = ((unsigned)u) << 16; return z.f;
}
__device__ inline unsigned short f2bf(float f) {
  union { float f; unsigned u; } z; z.f = f;
  unsigned r = z.u + 0x7fffu + ((z.u >> 16) & 1u);
  return (unsigned short)(r >> 16);
}
__device__ inline void gload_lds16(const void* g, void* l) {
  __builtin_amdgcn_global_load_lds((const __attribute__((address_space(1))) void*)g,
                                   (__attribute__((address_space(3))) void*)l, 16, 0, 0);
}

// ---------- mega convert: all f32->bf16 conversions + rpe pack, one launch ----------
__global__ __launch_bounds__(256) void mega_cvt(
    const float* __restrict__ x, const float* __restrict__ mem,
    const float* __restrict__ Wq, const float* __restrict__ Wk, const float* __restrict__ Wv,
    const float* __restrict__ Wo, const float* __restrict__ We, const float* __restrict__ Ws,
    const float* __restrict__ Wrpe, const float* __restrict__ brpe,
    unsigned short* __restrict__ xb, unsigned short* __restrict__ mb,
    unsigned short* __restrict__ wqb, unsigned short* __restrict__ wkvb,
    unsigned short* __restrict__ wob, unsigned short* __restrict__ web,
    unsigned short* __restrict__ wsb, float4* __restrict__ rpe4) {
  const int b = blockIdx.x, t = threadIdx.x;
  const float* src; unsigned short* dst; long off;
  if (b < 2048)      { src = x;   dst = xb;            off = (long)b * 1024; }
  else if (b < 4096) { src = mem; dst = mb;            off = (long)(b - 2048) * 1024; }
  else if (b < 4160) { src = Wq;  dst = wqb;           off = (long)(b - 4096) * 1024; }
  else if (b < 4224) { src = Wk;  dst = wkvb;          off = (long)(b - 4160) * 1024; }
  else if (b < 4288) { src = Wv;  dst = wkvb + 65536;  off = (long)(b - 4224) * 1024; }
  else if (b < 4352) { src = Wo;  dst = wob;           off = (long)(b - 4288) * 1024; }
  else if (b < 4480) { src = We;  dst = web;           off = (long)(b - 4352) * 1024; }
  else if (b < 4608) { src = Ws;  dst = wsb;           off = (long)(b - 4480) * 1024; }
  else {
    if (t < 128) {
      float4 r;
      r.x = Wrpe[3 * t]; r.y = Wrpe[3 * t + 1]; r.z = Wrpe[3 * t + 2]; r.w = brpe[t];
      rpe4[t] = r;
    }
    return;
  }
  const float4 v = *(const float4*)(src + off + t * 4);
  ushort4 o;
  o.x = f2bf(v.x); o.y = f2bf(v.y); o.z = f2bf(v.z); o.w = f2bf(v.w);
  *(ushort4*)(dst + off + t * 4) = o;
}

// ---------- bf16 NT GEMM: out[m][o] = sum_k A[m][k]*W[o][k] + bias[o] ----------
// EPI: 0=f32, 1=bf16, 2=relu+bf16, 3=+res f32, 4=split bf16 (kv)
template <int BM, int BN, int EPI>
__global__ __launch_bounds__(256, 2) void gemm_bt(
    const unsigned short* __restrict__ A,   // M x K (bf16 bits)
    const unsigned short* __restrict__ W,   // O x K (bf16 bits)
    const float* __restrict__ bias,         // O (or first half for EPI4)
    const float* __restrict__ bias2,        // second half bias (EPI4)
    const float* __restrict__ res,          // M x O (EPI3)
    float* __restrict__ outf,
    unsigned short* __restrict__ outb,
    unsigned short* __restrict__ outb2,     // EPI4 second buffer
    int K, int O) {
  constexpr int FM = BM / 32, FN = BN / 32;
  __shared__ __attribute__((aligned(16))) char lds[(BM + BN) * 64];
  const int tid = threadIdx.x, lane = tid & 63;
  const int wm = tid >> 7, wo = (tid >> 6) & 1;
  const long bm = blockIdx.x, bo = blockIdx.y;

  f32x4 acc[FM][FN] = {};
  const int nk = K >> 5;
  const long rowbytes = (long)K * 2;
  const char* Ab = (const char*)(A + bm * BM * (long)K);
  const char* Wb = (const char*)(W + bo * BN * (long)K);

  for (int kt = 0; kt < nk; ++kt) {
#pragma unroll
    for (int c = 0; c < BM / 64; ++c) {
      const int fb = c * 4096 + tid * 16;
      gload_lds16(Ab + (fb >> 6) * rowbytes + kt * 64 + (fb & 63), lds + fb);
    }
#pragma unroll
    for (int c = 0; c < BN / 64; ++c) {
      const int fb = c * 4096 + tid * 16;
      gload_lds16(Wb + (fb >> 6) * rowbytes + kt * 64 + (fb & 63), lds + BM * 64 + fb);
    }
    __syncthreads();
    bf16x8 af[FM], bfr[FN];
    const int kb = (lane >> 4) * 16;
#pragma unroll
    for (int i = 0; i < FM; ++i)
      af[i] = *(const bf16x8*)(lds + (wm * (BM / 2) + i * 16 + (lane & 15)) * 64 + kb);
#pragma unroll
    for (int j = 0; j < FN; ++j)
      bfr[j] = *(const bf16x8*)(lds + BM * 64 + (wo * (BN / 2) + j * 16 + (lane & 15)) * 64 + kb);
#pragma unroll
    for (int i = 0; i < FM; ++i)
#pragma unroll
      for (int j = 0; j < FN; ++j)
        acc[i][j] = __builtin_amdgcn_mfma_f32_16x16x32_bf16(af[i], bfr[j], acc[i][j], 0, 0, 0);
    __syncthreads();
  }

#pragma unroll
  for (int i = 0; i < FM; ++i) {
#pragma unroll
    for (int j = 0; j < FN; ++j) {
      const int colg = (int)bo * BN + wo * (BN / 2) + j * 16 + (lane & 15);
      const int half = O >> 1;
      const float bv = (EPI == 4 && colg >= half) ? bias2[colg - half] : bias[colg];
#pragma unroll
      for (int r = 0; r < 4; ++r) {
        const long rowg = bm * BM + wm * (BM / 2) + i * 16 + (lane >> 4) * 4 + r;
        float v = acc[i][j][r] + bv;
        if (EPI == 3) v += res[rowg * O + colg];
        if (EPI == 0 || EPI == 3) outf[rowg * O + colg] = v;
        else if (EPI == 1) outb[rowg * O + colg] = f2bf(v);
        else if (EPI == 2) outb[rowg * O + colg] = f2bf(v > 0.f ? v : 0.f);
        else if (EPI == 4) {
          if (colg < half) outb[rowg * half + colg] = f2bf(v);
          else outb2[rowg * half + colg - half] = f2bf(v);
        }
      }
    }
  }
}

// ---------- fused gather + RPE rotary + MHA, register-resident K/q ----------
// thread t: h = t>>5 (head), k = t&31 (neighbor). One query per block.
__global__ __launch_bounds__(256, 4) void attn2(
    const unsigned short* __restrict__ qb,   // N x 256 (bf16)
    const unsigned short* __restrict__ kbp,  // M x 256 (bf16)
    const unsigned short* __restrict__ vbp,  // M x 256 (bf16)
    const int* __restrict__ idx,             // N x 32
    const float* __restrict__ icoord,        // N x 3
    const float* __restrict__ mcoord,        // M x 3
    const float* __restrict__ mask,          // N x 32
    const float4* __restrict__ rpe4,         // 128 x {w0,w1,w2,b}
    unsigned short* __restrict__ hb)         // N x 256 (bf16)
{
  __shared__ int idx_s[32];
  __shared__ float4 relm_s[32];              // {rx,ry,rz,mask}
  __shared__ float4 rpe_s[128];
  __shared__ float p_s[256];
  __shared__ __attribute__((aligned(16))) unsigned short vls[32][256];

  const int n = blockIdx.x, t = threadIdx.x;
  if (t < 128) rpe_s[t] = rpe4[t];
  if (t < 32) {
    const int m = idx[n * 32 + t];
    idx_s[t] = m;
    float4 rm;
    rm.x = mcoord[(long)m * 3 + 0] - icoord[(long)n * 3 + 0];
    rm.y = mcoord[(long)m * 3 + 1] - icoord[(long)n * 3 + 1];
    rm.z = mcoord[(long)m * 3 + 2] - icoord[(long)n * 3 + 2];
    rm.w = mask[n * 32 + t];
    relm_s[t] = rm;
  }
  __syncthreads();

  // stage V (16KB) into LDS, overlapped with score computation below.
  // dest = wave-uniform base + lane*16 (b = i*4096 + t*16).
#pragma unroll
  for (int i = 0; i < 4; ++i) {
    const int b = i * 4096 + t * 16;
    const int r = b >> 9, cb = b & 511;
    gload_lds16((const char*)vbp + (long)idx_s[r] * 512 + cb, (char*)vls + b);
  }

  const int h = t >> 5, k = t & 31;
  const float4 rm = relm_s[k];
  const long krow = idx_s[k];

  u16x8 kv8[4], qv8[4];
  {
    const u16x8* kp = (const u16x8*)(kbp + krow * 256 + h * 32);
    const u16x8* qp = (const u16x8*)(qb + (long)n * 256 + h * 32);
#pragma unroll
    for (int i = 0; i < 4; ++i) { kv8[i] = kp[i]; qv8[i] = qp[i]; }
  }

  float sc = 0.f;
#pragma unroll
  for (int j2 = 0; j2 < 16; ++j2) {
    const float4 wj = rpe_s[h * 16 + j2];
    const float ang = fmaf(wj.x, rm.x, fmaf(wj.y, rm.y, fmaf(wj.z, rm.z, wj.w)));
    float sn, cs;
    __sincosf(ang, &sn, &cs);
    const int wi = j2 >> 2, e0 = (j2 & 3) * 2;
    const float x0 = bf2f(kv8[wi][e0]), x1 = bf2f(kv8[wi][e0 + 1]);
    const float q0 = bf2f(qv8[wi][e0]), q1 = bf2f(qv8[wi][e0 + 1]);
    const float k0 = fmaf(x0, cs, -x1 * sn);
    const float k1 = fmaf(x0, sn, x1 * cs);
    sc = fmaf(q0, k0, sc);
    sc = fmaf(q1, k1, sc);
  }
  sc = sc * 0.17677669529663687f - 1e6f * (1.f - rm.w);

  // softmax over k: butterflies within the 32-lane group
  float mx = sc;
#pragma unroll
  for (int m = 16; m > 0; m >>= 1) mx = fmaxf(mx, __shfl_xor(mx, m, 32));
  const float e = __expf(sc - mx);
  float sum = e;
#pragma unroll
  for (int m = 16; m > 0; m >>= 1) sum += __shfl_xor(sum, m, 32);
  p_s[t] = e / sum;  // p_s[h*32 + k]
  __syncthreads();   // vls staging complete; p_s visible to all waves

  // PV: thread t = output channel
  float acc = 0.f;
  const int h2 = t >> 5;
#pragma unroll
  for (int k4 = 0; k4 < 8; ++k4) {
    const float4 p4 = *(const float4*)(p_s + h2 * 32 + k4 * 4);
    acc = fmaf(p4.x, bf2f(vls[k4 * 4 + 0][t]), acc);
    acc = fmaf(p4.y, bf2f(vls[k4 * 4 + 1][t]), acc);
    acc = fmaf(p4.z, bf2f(vls[k4 * 4 + 2][t]), acc);
    acc = fmaf(p4.w, bf2f(vls[k4 * 4 + 3][t]), acc);
  }
  hb[(long)n * 256 + t] = f2bf(acc);
}

// ---------- row LayerNorm over C=256 (wave per row, 4 rows/block) ----------
template <int WRITE_B>
__global__ __launch_bounds__(256) void ln_kernel(
    const float* __restrict__ in, const float* __restrict__ g, const float* __restrict__ b,
    float* __restrict__ outf, unsigned short* __restrict__ outb) {
  const long row = (long)blockIdx.x * 4 + (threadIdx.x >> 6);
  const int lane = threadIdx.x & 63;
  const float4 x = *(const float4*)(in + row * 256 + lane * 4);
  float s = x.x + x.y + x.z + x.w;
  float s2 = fmaf(x.x, x.x, fmaf(x.y, x.y, fmaf(x.z, x.z, x.w * x.w)));
#pragma unroll
  for (int o = 32; o > 0; o >>= 1) { s += __shfl_xor(s, o, 64); s2 += __shfl_xor(s2, o, 64); }
  const float mu = s * (1.f / 256.f);
  const float var = s2 * (1.f / 256.f) - mu * mu;
  const float inv = rsqrtf(var + 1e-5f);
  const float4 gv = *(const float4*)(g + lane * 4);
  const float4 bv = *(const float4*)(b + lane * 4);
  float4 y;
  y.x = (x.x - mu) * inv * gv.x + bv.x;
  y.y = (x.y - mu) * inv * gv.y + bv.y;
  y.z = (x.z - mu) * inv * gv.z + bv.z;
  y.w = (x.w - mu) * inv * gv.w + bv.w;
  *(float4*)(outf + row * 256 + lane * 4) = y;
  if (WRITE_B) {
    ushort4 yb;
    yb.x = f2bf(y.x); yb.y = f2bf(y.y); yb.z = f2bf(y.z); yb.w = f2bf(y.w);
    *(ushort4*)(outb + row * 256 + lane * 4) = yb;
  }
}

// ---------- launch ----------
extern "C" void kernel_launch(void* const* d_in, const int* in_sizes, int n_in,
                              void* d_out, int out_size, void* d_ws, size_t ws_size,
                              hipStream_t stream) {
  const float* x    = (const float*)d_in[0];
  const float* mem  = (const float*)d_in[1];
  const int* idx    = (const int*)d_in[2];
  const float* ic   = (const float*)d_in[3];
  const float* mc   = (const float*)d_in[4];
  const float* mask = (const float*)d_in[5];
  const float* Wq = (const float*)d_in[6];  const float* bq = (const float*)d_in[7];
  const float* Wk = (const float*)d_in[8];  const float* bk = (const float*)d_in[9];
  const float* Wv = (const float*)d_in[10]; const float* bv = (const float*)d_in[11];
  const float* Wo = (const float*)d_in[12]; const float* bo = (const float*)d_in[13];
  const float* g1 = (const float*)d_in[14]; const float* b1 = (const float*)d_in[15];
  const float* Wrpe = (const float*)d_in[16]; const float* brpe = (const float*)d_in[17];
  const float* We = (const float*)d_in[18]; const float* be = (const float*)d_in[19];
  const float* Ws = (const float*)d_in[20]; const float* bs = (const float*)d_in[21];
  const float* g2 = (const float*)d_in[22]; const float* b2 = (const float*)d_in[23];

  char* w = (char*)d_ws;
  const size_t MB = 1ull << 20;
  unsigned short* xb    = (unsigned short*)(w + 0);        // 4MB, dead after q-gemm
  unsigned short* mb    = (unsigned short*)(w + 4 * MB);   // 4MB, dead after kv-gemm
  unsigned short* kbp   = (unsigned short*)(w + 8 * MB);   // 4MB, dead after attn
  unsigned short* vbp   = (unsigned short*)(w + 12 * MB);  // 4MB, dead after attn
  unsigned short* qbuf  = (unsigned short*)(w + 16 * MB);  // 4MB, dead after attn
  unsigned short* hb    = (unsigned short*)(w + 20 * MB);  // 4MB, dead after o-gemm
  float*          out1  = (float*)(w + 24 * MB);           // 8MB, live till ffn2
  unsigned short* out1b = (unsigned short*)(w + 32 * MB);  // 4MB, dead after ffn1
  float*          t1    = (float*)(w + 0);                 // 8MB, overlays xb+mb
  unsigned short* ffb   = (unsigned short*)(w + 8 * MB);   // 8MB, overlays kbp+vbp
  float*          t2    = (float*)(w + 16 * MB);           // 8MB, overlays qbuf+hb
  unsigned short* wqb  = (unsigned short*)(w + 36 * MB);           // 128KB
  unsigned short* wkvb = wqb + 65536;                               // 256KB (Wk|Wv)
  unsigned short* wob  = wkvb + 131072;                             // 128KB
  unsigned short* web  = wob + 65536;                               // 256KB
  unsigned short* wsb  = web + 131072;                              // 256KB
  float4*         rpe4 = (float4*)(wsb + 131072);                   // 2KB

  mega_cvt<<<4609, 256, 0, stream>>>(x, mem, Wq, Wk, Wv, Wo, We, Ws, Wrpe, brpe,
                                     xb, mb, wqb, wkvb, wob, web, wsb, rpe4);

  // projections: q (bf16 out), fused k|v (split bf16 out)
  gemm_bt<64, 128, 1><<<dim3(128, 2), 256, 0, stream>>>(
      xb, wqb, bq, nullptr, nullptr, nullptr, qbuf, nullptr, 256, 256);
  gemm_bt<64, 128, 4><<<dim3(128, 4), 256, 0, stream>>>(
      mb, wkvb, bk, bv, nullptr, nullptr, kbp, vbp, 256, 512);

  // fused gather + rotary + attention
  attn2<<<8192, 256, 0, stream>>>(qbuf, kbp, vbp, idx, ic, mc, mask, rpe4, hb);

  // output proj + residual, LN1
  gemm_bt<64, 128, 3><<<dim3(128, 2), 256, 0, stream>>>(
      hb, wob, bo, nullptr, x, t1, nullptr, nullptr, 256, 256);
  ln_kernel<1><<<2048, 256, 0, stream>>>(t1, g1, b1, out1, out1b);

  // FFN
  gemm_bt<64, 128, 2><<<dim3(128, 4), 256, 0, stream>>>(
      out1b, web, be, nullptr, nullptr, nullptr, ffb, nullptr, 256, 512);
  gemm_bt<64, 128, 3><<<dim3(128, 2), 256, 0, stream>>>(
      ffb, wsb, bs, nullptr, out1, t2, nullptr, nullptr, 512, 256);
  ln_kernel<0><<<2048, 256, 0, stream>>>(t2, g2, b2, (float*)d_out, nullptr);
}

// Round 4
// 90.724 us; speedup vs baseline: 1.6326x; 1.1836x over previous
//
#include <hip/hip_runtime.h>
#include <hip/hip_bf16.h>
#include <stdint.h>

// ---------- helpers ----------
typedef __attribute__((ext_vector_type(8))) __bf16 bf16x8;
typedef __attribute__((ext_vector_type(8))) unsigned short u16x8;
typedef __attribute__((ext_vector_type(4))) float f32x4;

__device__ inline float bf2f(unsigned short u) {
  union { unsigned u; float f; } z; z.u = ((unsigned)u) << 16; return z.f;
}
__device__ inline unsigned short f2bf(float f) {
  union { float f; unsigned u; } z; z.f = f;
  unsigned r = z.u + 0x7fffu + ((z.u >> 16) & 1u);
  return (unsigned short)(r >> 16);
}
__device__ inline void gload_lds16(const void* g, void* l) {
  __builtin_amdgcn_global_load_lds((const __attribute__((address_space(1))) void*)g,
                                   (__attribute__((address_space(3))) void*)l, 16, 0, 0);
}

// ---------- weight convert: f32->bf16 weights + rpe pack (513 blocks) ----------
__global__ __launch_bounds__(256) void wcvt(
    const float* __restrict__ Wq, const float* __restrict__ Wk, const float* __restrict__ Wv,
    const float* __restrict__ Wo, const float* __restrict__ We, const float* __restrict__ Ws,
    const float* __restrict__ Wrpe, const float* __restrict__ brpe,
    unsigned short* __restrict__ wqb, unsigned short* __restrict__ wkvb,
    unsigned short* __restrict__ wob, unsigned short* __restrict__ web,
    unsigned short* __restrict__ wsb, float4* __restrict__ rpe4) {
  const int b = blockIdx.x, t = threadIdx.x;
  const float* src; unsigned short* dst; long off;
  if (b < 64)       { src = Wq; dst = wqb;           off = (long)b * 1024; }
  else if (b < 128) { src = Wk; dst = wkvb;          off = (long)(b - 64) * 1024; }
  else if (b < 192) { src = Wv; dst = wkvb + 65536;  off = (long)(b - 128) * 1024; }
  else if (b < 256) { src = Wo; dst = wob;           off = (long)(b - 192) * 1024; }
  else if (b < 384) { src = We; dst = web;           off = (long)(b - 256) * 1024; }
  else if (b < 512) { src = Ws; dst = wsb;           off = (long)(b - 384) * 1024; }
  else {
    if (t < 128) {
      float4 r;
      r.x = Wrpe[3 * t]; r.y = Wrpe[3 * t + 1]; r.z = Wrpe[3 * t + 2]; r.w = brpe[t];
      rpe4[t] = r;
    }
    return;
  }
  const float4 v = *(const float4*)(src + off + t * 4);
  ushort4 o;
  o.x = f2bf(v.x); o.y = f2bf(v.y); o.z = f2bf(v.z); o.w = f2bf(v.w);
  *(ushort4*)(dst + off + t * 4) = o;
}

// ---------- fused q/k/v projection: f32 A, bf16 W, bf16 out ----------
// grid (128, 6): by 0-1 -> q (A=x), by 2-3 -> k, by 4-5 -> v (A=mem). BM=64, BN=128, K=256.
__global__ __launch_bounds__(256, 2) void gemm_proj(
    const float* __restrict__ x, const float* __restrict__ mem,
    const unsigned short* __restrict__ wqb, const unsigned short* __restrict__ wkvb,
    const float* __restrict__ bq, const float* __restrict__ bk, const float* __restrict__ bv,
    unsigned short* __restrict__ qbuf, unsigned short* __restrict__ kbp,
    unsigned short* __restrict__ vbp) {
  __shared__ __attribute__((aligned(16))) char lds[4096 + 8192];  // A 4KB | B 8KB
  const int tid = threadIdx.x, lane = tid & 63;
  const int wm = tid >> 7, wo = (tid >> 6) & 1;
  const long bm = blockIdx.x;
  const int by = blockIdx.y;

  const float* Ab; const unsigned short* Wb; const float* biasp; unsigned short* outp; int cb;
  if (by < 2)      { Ab = x;   Wb = wqb  + by * 128 * 256;       biasp = bq + by * 128;       outp = qbuf; cb = by * 128; }
  else if (by < 4) { Ab = mem; Wb = wkvb + (by - 2) * 128 * 256; biasp = bk + (by - 2) * 128; outp = kbp;  cb = (by - 2) * 128; }
  else             { Ab = mem; Wb = wkvb + (by - 2) * 128 * 256; biasp = bv + (by - 4) * 128; outp = vbp;  cb = (by - 4) * 128; }

  f32x4 acc[2][4] = {};
  for (int kt = 0; kt < 8; ++kt) {
    // A: 64 rows x 32 f32 (128B/row) -> bf16 LDS (64B/row), reg-staged
#pragma unroll
    for (int c = 0; c < 2; ++c) {
      const int fb = c * 4096 + tid * 16;       // byte in 64x128B f32 tile
      const int row = fb >> 7, colb = fb & 127;
      const float4 a4 = *(const float4*)((const char*)Ab + (bm * 64 + row) * 1024 + kt * 128 + colb);
      ushort4 o;
      o.x = f2bf(a4.x); o.y = f2bf(a4.y); o.z = f2bf(a4.z); o.w = f2bf(a4.w);
      *(ushort4*)(lds + row * 64 + (colb >> 1)) = o;
    }
    // B: 128 rows x 64B
#pragma unroll
    for (int c = 0; c < 2; ++c) {
      const int fb = c * 4096 + tid * 16;
      gload_lds16((const char*)Wb + (long)(fb >> 6) * 512 + kt * 64 + (fb & 63), lds + 4096 + fb);
    }
    __syncthreads();
    bf16x8 af[2], bfr[4];
    const int kb = (lane >> 4) * 16;
#pragma unroll
    for (int i = 0; i < 2; ++i)
      af[i] = *(const bf16x8*)(lds + (wm * 32 + i * 16 + (lane & 15)) * 64 + kb);
#pragma unroll
    for (int j = 0; j < 4; ++j)
      bfr[j] = *(const bf16x8*)(lds + 4096 + (wo * 64 + j * 16 + (lane & 15)) * 64 + kb);
#pragma unroll
    for (int i = 0; i < 2; ++i)
#pragma unroll
      for (int j = 0; j < 4; ++j)
        acc[i][j] = __builtin_amdgcn_mfma_f32_16x16x32_bf16(af[i], bfr[j], acc[i][j], 0, 0, 0);
    __syncthreads();
  }

#pragma unroll
  for (int i = 0; i < 2; ++i) {
#pragma unroll
    for (int j = 0; j < 4; ++j) {
      const int lc = wo * 64 + j * 16 + (lane & 15);
      const float bvv = biasp[lc];
#pragma unroll
      for (int r = 0; r < 4; ++r) {
        const long rowg = bm * 64 + wm * 32 + i * 16 + (lane >> 4) * 4 + r;
        outp[rowg * 256 + cb + lc] = f2bf(acc[i][j][r] + bvv);
      }
    }
  }
}

// ---------- bf16 GEMM + relu + bf16 out (FFN1). BM=64, BN=128 ----------
__global__ __launch_bounds__(256, 2) void gemm_relu(
    const unsigned short* __restrict__ A,   // M x 256
    const unsigned short* __restrict__ W,   // 512 x 256
    const float* __restrict__ bias,         // 512
    unsigned short* __restrict__ outb) {    // M x 512
  __shared__ __attribute__((aligned(16))) char lds[(64 + 128) * 64];
  const int tid = threadIdx.x, lane = tid & 63;
  const int wm = tid >> 7, wo = (tid >> 6) & 1;
  const long bm = blockIdx.x, bo = blockIdx.y;

  f32x4 acc[2][4] = {};
  const char* Ab = (const char*)(A + bm * 64 * 256);
  const char* Wb = (const char*)(W + bo * 128 * 256);
  for (int kt = 0; kt < 8; ++kt) {
    {
      const int fb = tid * 16;
      gload_lds16(Ab + (long)(fb >> 6) * 512 + kt * 64 + (fb & 63), lds + fb);
    }
#pragma unroll
    for (int c = 0; c < 2; ++c) {
      const int fb = c * 4096 + tid * 16;
      gload_lds16(Wb + (long)(fb >> 6) * 512 + kt * 64 + (fb & 63), lds + 4096 + fb);
    }
    __syncthreads();
    bf16x8 af[2], bfr[4];
    const int kb = (lane >> 4) * 16;
#pragma unroll
    for (int i = 0; i < 2; ++i)
      af[i] = *(const bf16x8*)(lds + (wm * 32 + i * 16 + (lane & 15)) * 64 + kb);
#pragma unroll
    for (int j = 0; j < 4; ++j)
      bfr[j] = *(const bf16x8*)(lds + 4096 + (wo * 64 + j * 16 + (lane & 15)) * 64 + kb);
#pragma unroll
    for (int i = 0; i < 2; ++i)
#pragma unroll
      for (int j = 0; j < 4; ++j)
        acc[i][j] = __builtin_amdgcn_mfma_f32_16x16x32_bf16(af[i], bfr[j], acc[i][j], 0, 0, 0);
    __syncthreads();
  }
#pragma unroll
  for (int i = 0; i < 2; ++i) {
#pragma unroll
    for (int j = 0; j < 4; ++j) {
      const int colg = (int)bo * 128 + wo * 64 + j * 16 + (lane & 15);
      const float bvv = bias[colg];
#pragma unroll
      for (int r = 0; r < 4; ++r) {
        const long rowg = bm * 64 + wm * 32 + i * 16 + (lane >> 4) * 4 + r;
        const float v = acc[i][j][r] + bvv;
        outb[rowg * 512 + colg] = f2bf(v > 0.f ? v : 0.f);
      }
    }
  }
}

// ---------- GEMM + bias + residual + LayerNorm fused epilogue ----------
// BM=32, BN=256 (full row per block), grid (M/32). KT = K/32.
template <int KT, int WRITE_B>
__global__ __launch_bounds__(256, 2) void gemm_ln(
    const unsigned short* __restrict__ A,   // M x K bf16
    const unsigned short* __restrict__ W,   // 256 x K bf16
    const float* __restrict__ bias,         // 256
    const float* __restrict__ res,          // M x 256 f32
    const float* __restrict__ g, const float* __restrict__ b,
    float* __restrict__ outf,               // M x 256 f32
    unsigned short* __restrict__ outb) {    // M x 256 bf16 (WRITE_B)
  __shared__ __attribute__((aligned(16))) char lds[2048 + 16384];  // A 2KB | B 16KB
  __shared__ float2 part[2][32];
  const int tid = threadIdx.x, lane = tid & 63;
  const int wm = tid >> 7, wo = (tid >> 6) & 1;
  const long bm = blockIdx.x;
  constexpr int K = KT * 32;

  f32x4 acc[8] = {};
  const char* Ab = (const char*)(A + bm * 32 * (long)K);
  for (int kt = 0; kt < KT; ++kt) {
    if (tid < 128) {
      const int fb = tid * 16;
      gload_lds16(Ab + (long)(fb >> 6) * (K * 2) + kt * 64 + (fb & 63), lds + fb);
    }
#pragma unroll
    for (int c = 0; c < 4; ++c) {
      const int fb = c * 4096 + tid * 16;
      gload_lds16((const char*)W + (long)(fb >> 6) * (K * 2) + kt * 64 + (fb & 63), lds + 2048 + fb);
    }
    __syncthreads();
    bf16x8 af, bfr[8];
    const int kb = (lane >> 4) * 16;
    af = *(const bf16x8*)(lds + (wm * 16 + (lane & 15)) * 64 + kb);
#pragma unroll
    for (int j = 0; j < 8; ++j)
      bfr[j] = *(const bf16x8*)(lds + 2048 + (wo * 128 + j * 16 + (lane & 15)) * 64 + kb);
#pragma unroll
    for (int j = 0; j < 8; ++j)
      acc[j] = __builtin_amdgcn_mfma_f32_16x16x32_bf16(af, bfr[j], acc[j], 0, 0, 0);
    __syncthreads();
  }

  // epilogue: v = acc + bias + res; LN over 256 cols per row
  float gj[8], bj[8], biasj[8];
  int colg[8];
#pragma unroll
  for (int j = 0; j < 8; ++j) {
    colg[j] = wo * 128 + j * 16 + (lane & 15);
    gj[j] = g[colg[j]]; bj[j] = b[colg[j]]; biasj[j] = bias[colg[j]];
  }
  float v[8][4];
#pragma unroll
  for (int r = 0; r < 4; ++r) {
    const int row_local = wm * 16 + (lane >> 4) * 4 + r;
    const long rowg = bm * 32 + row_local;
    float s = 0.f, s2 = 0.f;
#pragma unroll
    for (int j = 0; j < 8; ++j) {
      float vv = acc[j][r] + biasj[j] + res[rowg * 256 + colg[j]];
      v[j][r] = vv;
      s += vv; s2 = fmaf(vv, vv, s2);
    }
#pragma unroll
    for (int m = 8; m > 0; m >>= 1) { s += __shfl_xor(s, m, 64); s2 += __shfl_xor(s2, m, 64); }
    if ((lane & 15) == 0) part[wo][row_local] = make_float2(s, s2);
  }
  __syncthreads();
#pragma unroll
  for (int r = 0; r < 4; ++r) {
    const int row_local = wm * 16 + (lane >> 4) * 4 + r;
    const long rowg = bm * 32 + row_local;
    const float2 p0 = part[0][row_local], p1 = part[1][row_local];
    const float mu = (p0.x + p1.x) * (1.f / 256.f);
    const float var = (p0.y + p1.y) * (1.f / 256.f) - mu * mu;
    const float inv = rsqrtf(var + 1e-5f);
#pragma unroll
    for (int j = 0; j < 8; ++j) {
      const float y = (v[j][r] - mu) * inv * gj[j] + bj[j];
      outf[rowg * 256 + colg[j]] = y;
      if (WRITE_B) outb[rowg * 256 + colg[j]] = f2bf(y);
    }
  }
}

// ---------- fused gather + RPE rotary + MHA, register-resident K/q ----------
__global__ __launch_bounds__(256, 4) void attn2(
    const unsigned short* __restrict__ qb,   // N x 256 (bf16)
    const unsigned short* __restrict__ kbp,  // M x 256 (bf16)
    const unsigned short* __restrict__ vbp,  // M x 256 (bf16)
    const int* __restrict__ idx,             // N x 32
    const float* __restrict__ icoord,        // N x 3
    const float* __restrict__ mcoord,        // M x 3
    const float* __restrict__ mask,          // N x 32
    const float4* __restrict__ rpe4,         // 128 x {w0,w1,w2,b}
    unsigned short* __restrict__ hb)         // N x 256 (bf16)
{
  __shared__ int idx_s[32];
  __shared__ float4 relm_s[32];
  __shared__ float4 rpe_s[128];
  __shared__ float p_s[256];
  __shared__ __attribute__((aligned(16))) unsigned short vls[32][256];

  const int n = blockIdx.x, t = threadIdx.x;
  if (t < 128) rpe_s[t] = rpe4[t];
  if (t < 32) {
    const int m = idx[n * 32 + t];
    idx_s[t] = m;
    float4 rm;
    rm.x = mcoord[(long)m * 3 + 0] - icoord[(long)n * 3 + 0];
    rm.y = mcoord[(long)m * 3 + 1] - icoord[(long)n * 3 + 1];
    rm.z = mcoord[(long)m * 3 + 2] - icoord[(long)n * 3 + 2];
    rm.w = mask[n * 32 + t];
    relm_s[t] = rm;
  }
  __syncthreads();

#pragma unroll
  for (int i = 0; i < 4; ++i) {
    const int b = i * 4096 + t * 16;
    const int r = b >> 9, cb = b & 511;
    gload_lds16((const char*)vbp + (long)idx_s[r] * 512 + cb, (char*)vls + b);
  }

  const int h = t >> 5, k = t & 31;
  const float4 rm = relm_s[k];
  const long krow = idx_s[k];

  u16x8 kv8[4], qv8[4];
  {
    const u16x8* kp = (const u16x8*)(kbp + krow * 256 + h * 32);
    const u16x8* qp = (const u16x8*)(qb + (long)n * 256 + h * 32);
#pragma unroll
    for (int i = 0; i < 4; ++i) { kv8[i] = kp[i]; qv8[i] = qp[i]; }
  }

  float sc = 0.f;
#pragma unroll
  for (int j2 = 0; j2 < 16; ++j2) {
    const float4 wj = rpe_s[h * 16 + j2];
    const float ang = fmaf(wj.x, rm.x, fmaf(wj.y, rm.y, fmaf(wj.z, rm.z, wj.w)));
    float sn, cs;
    __sincosf(ang, &sn, &cs);
    const int wi = j2 >> 2, e0 = (j2 & 3) * 2;
    const float x0 = bf2f(kv8[wi][e0]), x1 = bf2f(kv8[wi][e0 + 1]);
    const float q0 = bf2f(qv8[wi][e0]), q1 = bf2f(qv8[wi][e0 + 1]);
    const float k0 = fmaf(x0, cs, -x1 * sn);
    const float k1 = fmaf(x0, sn, x1 * cs);
    sc = fmaf(q0, k0, sc);
    sc = fmaf(q1, k1, sc);
  }
  sc = sc * 0.17677669529663687f - 1e6f * (1.f - rm.w);

  float mx = sc;
#pragma unroll
  for (int m = 16; m > 0; m >>= 1) mx = fmaxf(mx, __shfl_xor(mx, m, 32));
  const float e = __expf(sc - mx);
  float sum = e;
#pragma unroll
  for (int m = 16; m > 0; m >>= 1) sum += __shfl_xor(sum, m, 32);
  p_s[t] = e / sum;
  __syncthreads();

  float acc = 0.f;
  const int h2 = t >> 5;
#pragma unroll
  for (int k4 = 0; k4 < 8; ++k4) {
    const float4 p4 = *(const float4*)(p_s + h2 * 32 + k4 * 4);
    acc = fmaf(p4.x, bf2f(vls[k4 * 4 + 0][t]), acc);
    acc = fmaf(p4.y, bf2f(vls[k4 * 4 + 1][t]), acc);
    acc = fmaf(p4.z, bf2f(vls[k4 * 4 + 2][t]), acc);
    acc = fmaf(p4.w, bf2f(vls[k4 * 4 + 3][t]), acc);
  }
  hb[(long)n * 256 + t] = f2bf(acc);
}

// ---------- launch ----------
extern "C" void kernel_launch(void* const* d_in, const int* in_sizes, int n_in,
                              void* d_out, int out_size, void* d_ws, size_t ws_size,
                              hipStream_t stream) {
  const float* x    = (const float*)d_in[0];
  const float* mem  = (const float*)d_in[1];
  const int* idx    = (const int*)d_in[2];
  const float* ic   = (const float*)d_in[3];
  const float* mc   = (const float*)d_in[4];
  const float* mask = (const float*)d_in[5];
  const float* Wq = (const float*)d_in[6];  const float* bq = (const float*)d_in[7];
  const float* Wk = (const float*)d_in[8];  const float* bk = (const float*)d_in[9];
  const float* Wv = (const float*)d_in[10]; const float* bv = (const float*)d_in[11];
  const float* Wo = (const float*)d_in[12]; const float* bo = (const float*)d_in[13];
  const float* g1 = (const float*)d_in[14]; const float* b1 = (const float*)d_in[15];
  const float* Wrpe = (const float*)d_in[16]; const float* brpe = (const float*)d_in[17];
  const float* We = (const float*)d_in[18]; const float* be = (const float*)d_in[19];
  const float* Ws = (const float*)d_in[20]; const float* bs = (const float*)d_in[21];
  const float* g2 = (const float*)d_in[22]; const float* b2 = (const float*)d_in[23];

  char* w = (char*)d_ws;
  const size_t MB = 1ull << 20;
  unsigned short* kbp   = (unsigned short*)(w + 0);        // 4MB
  unsigned short* vbp   = (unsigned short*)(w + 4 * MB);   // 4MB
  unsigned short* qbuf  = (unsigned short*)(w + 8 * MB);   // 4MB
  unsigned short* hb    = (unsigned short*)(w + 12 * MB);  // 4MB
  float*          out1  = (float*)(w + 16 * MB);           // 8MB
  unsigned short* out1b = (unsigned short*)(w + 24 * MB);  // 4MB
  unsigned short* ffb   = (unsigned short*)(w + 28 * MB);  // 8MB (8192x512 bf16)
  unsigned short* wqb  = (unsigned short*)(w + 36 * MB);   // 128KB
  unsigned short* wkvb = wqb + 65536;                      // 256KB (Wk|Wv)
  unsigned short* wob  = wkvb + 131072;                    // 128KB
  unsigned short* web  = wob + 65536;                      // 256KB
  unsigned short* wsb  = web + 131072;                     // 256KB
  float4*         rpe4 = (float4*)(wsb + 131072);          // 2KB

  wcvt<<<513, 256, 0, stream>>>(Wq, Wk, Wv, Wo, We, Ws, Wrpe, brpe,
                                wqb, wkvb, wob, web, wsb, rpe4);

  // fused q/k/v projections (f32 A, reg-staged cvt)
  gemm_proj<<<dim3(128, 6), 256, 0, stream>>>(x, mem, wqb, wkvb, bq, bk, bv, qbuf, kbp, vbp);

  // fused gather + rotary + attention
  attn2<<<8192, 256, 0, stream>>>(qbuf, kbp, vbp, idx, ic, mc, mask, rpe4, hb);

  // output proj + residual + LN1 (fused)
  gemm_ln<8, 1><<<256, 256, 0, stream>>>(hb, wob, bo, x, g1, b1, out1, out1b);

  // FFN1 (relu)
  gemm_relu<<<dim3(128, 4), 256, 0, stream>>>(out1b, web, be, ffb);

  // FFN2 + residual + LN2 (fused) -> d_out
  gemm_ln<16, 0><<<256, 256, 0, stream>>>(ffb, wsb, bs, out1, g2, b2, (float*)d_out, nullptr);
}

// Round 5
// 82.638 us; speedup vs baseline: 1.7923x; 1.0979x over previous
//
#include <hip/hip_runtime.h>
#include <hip/hip_bf16.h>
#include <stdint.h>

// ---------- helpers ----------
typedef __attribute__((ext_vector_type(8))) __bf16 bf16x8;
typedef __attribute__((ext_vector_type(8))) unsigned short u16x8;
typedef __attribute__((ext_vector_type(4))) float f32x4;

__device__ inline float bf2f(unsigned short u) {
  union { unsigned u; float f; } z; z.u = ((unsigned)u) << 16; return z.f;
}
__device__ inline unsigned short f2bf(float f) {
  union { float f; unsigned u; } z; z.f = f;
  unsigned r = z.u + 0x7fffu + ((z.u >> 16) & 1u);
  return (unsigned short)(r >> 16);
}
__device__ inline void gload_lds16(const void* g, void* l) {
  __builtin_amdgcn_global_load_lds((const __attribute__((address_space(1))) void*)g,
                                   (__attribute__((address_space(3))) void*)l, 16, 0, 0);
}

// ---------- fused q/k/v projection (f32 A and W, inline cvt) + weight conversions ----------
// grid (128, 7): by 0-1 -> q (A=x), 2-3 -> k, 4-5 -> v (A=mem); by==6 -> convert Wo/We/Ws/rpe.
__global__ __launch_bounds__(256, 2) void gemm_proj(
    const float* __restrict__ x, const float* __restrict__ mem,
    const float* __restrict__ Wq, const float* __restrict__ Wk, const float* __restrict__ Wv,
    const float* __restrict__ Wo, const float* __restrict__ We, const float* __restrict__ Ws,
    const float* __restrict__ Wrpe, const float* __restrict__ brpe,
    const float* __restrict__ bq, const float* __restrict__ bk, const float* __restrict__ bv,
    unsigned short* __restrict__ qbuf, unsigned short* __restrict__ kbp,
    unsigned short* __restrict__ vbp,
    unsigned short* __restrict__ wob, unsigned short* __restrict__ web,
    unsigned short* __restrict__ wsb, float4* __restrict__ rpe4) {
  const int tid = threadIdx.x;
  const int by = blockIdx.y;
  const long bm = blockIdx.x;

  if (by == 6) {
    // weight conversion lane: 321 chunks of 1024 floats, grid-strided over 128 blocks
#pragma unroll
    for (int it = 0; it < 3; ++it) {
      const int j = (int)bm + 128 * it;
      if (j < 64) {
        const float4 v = *(const float4*)(Wo + (long)j * 1024 + tid * 4);
        ushort4 o; o.x = f2bf(v.x); o.y = f2bf(v.y); o.z = f2bf(v.z); o.w = f2bf(v.w);
        *(ushort4*)(wob + (long)j * 1024 + tid * 4) = o;
      } else if (j < 192) {
        const float4 v = *(const float4*)(We + (long)(j - 64) * 1024 + tid * 4);
        ushort4 o; o.x = f2bf(v.x); o.y = f2bf(v.y); o.z = f2bf(v.z); o.w = f2bf(v.w);
        *(ushort4*)(web + (long)(j - 64) * 1024 + tid * 4) = o;
      } else if (j < 320) {
        const float4 v = *(const float4*)(Ws + (long)(j - 192) * 1024 + tid * 4);
        ushort4 o; o.x = f2bf(v.x); o.y = f2bf(v.y); o.z = f2bf(v.z); o.w = f2bf(v.w);
        *(ushort4*)(wsb + (long)(j - 192) * 1024 + tid * 4) = o;
      } else if (j == 320) {
        if (tid < 128) {
          float4 r;
          r.x = Wrpe[3 * tid]; r.y = Wrpe[3 * tid + 1]; r.z = Wrpe[3 * tid + 2]; r.w = brpe[tid];
          rpe4[tid] = r;
        }
      }
    }
    return;
  }

  __shared__ __attribute__((aligned(16))) char lds[4096 + 8192];  // A 4KB | B 8KB (bf16)
  const int lane = tid & 63;
  const int wm = tid >> 7, wo = (tid >> 6) & 1;

  const float* Ab; const float* Wf; const float* biasp; unsigned short* outp; int cb;
  if (by < 2)      { Ab = x;   Wf = Wq + (long)by * 128 * 256;       biasp = bq + by * 128;       outp = qbuf; cb = by * 128; }
  else if (by < 4) { Ab = mem; Wf = Wk + (long)(by - 2) * 128 * 256; biasp = bk + (by - 2) * 128; outp = kbp;  cb = (by - 2) * 128; }
  else             { Ab = mem; Wf = Wv + (long)(by - 4) * 128 * 256; biasp = bv + (by - 4) * 128; outp = vbp;  cb = (by - 4) * 128; }

  f32x4 acc[2][4] = {};
  for (int kt = 0; kt < 8; ++kt) {
    // A: 64 rows x 32 f32 (128B/row f32) -> bf16 LDS (64B/row)
#pragma unroll
    for (int c = 0; c < 2; ++c) {
      const int fb = c * 4096 + tid * 16;
      const int row = fb >> 7, colb = fb & 127;
      const float4 a4 = *(const float4*)((const char*)Ab + (bm * 64 + row) * 1024 + kt * 128 + colb);
      ushort4 o; o.x = f2bf(a4.x); o.y = f2bf(a4.y); o.z = f2bf(a4.z); o.w = f2bf(a4.w);
      *(ushort4*)(lds + row * 64 + (colb >> 1)) = o;
    }
    // W: 128 rows x 32 f32 -> bf16 LDS
#pragma unroll
    for (int c = 0; c < 4; ++c) {
      const int fb = c * 4096 + tid * 16;
      const int row = fb >> 7, colb = fb & 127;
      const float4 a4 = *(const float4*)((const char*)Wf + (long)row * 1024 + kt * 128 + colb);
      ushort4 o; o.x = f2bf(a4.x); o.y = f2bf(a4.y); o.z = f2bf(a4.z); o.w = f2bf(a4.w);
      *(ushort4*)(lds + 4096 + row * 64 + (colb >> 1)) = o;
    }
    __syncthreads();
    bf16x8 af[2], bfr[4];
    const int kb = (lane >> 4) * 16;
#pragma unroll
    for (int i = 0; i < 2; ++i)
      af[i] = *(const bf16x8*)(lds + (wm * 32 + i * 16 + (lane & 15)) * 64 + kb);
#pragma unroll
    for (int j = 0; j < 4; ++j)
      bfr[j] = *(const bf16x8*)(lds + 4096 + (wo * 64 + j * 16 + (lane & 15)) * 64 + kb);
#pragma unroll
    for (int i = 0; i < 2; ++i)
#pragma unroll
      for (int j = 0; j < 4; ++j)
        acc[i][j] = __builtin_amdgcn_mfma_f32_16x16x32_bf16(af[i], bfr[j], acc[i][j], 0, 0, 0);
    __syncthreads();
  }

#pragma unroll
  for (int i = 0; i < 2; ++i) {
#pragma unroll
    for (int j = 0; j < 4; ++j) {
      const int lc = wo * 64 + j * 16 + (lane & 15);
      const float bvv = biasp[lc];
#pragma unroll
      for (int r = 0; r < 4; ++r) {
        const long rowg = bm * 64 + wm * 32 + i * 16 + (lane >> 4) * 4 + r;
        outp[rowg * 256 + cb + lc] = f2bf(acc[i][j][r] + bvv);
      }
    }
  }
}

// ---------- bf16 GEMM + relu + bf16 out (FFN1). BM=64, BN=128 ----------
__global__ __launch_bounds__(256, 2) void gemm_relu(
    const unsigned short* __restrict__ A,   // M x 256
    const unsigned short* __restrict__ W,   // 512 x 256
    const float* __restrict__ bias,         // 512
    unsigned short* __restrict__ outb) {    // M x 512
  __shared__ __attribute__((aligned(16))) char lds[(64 + 128) * 64];
  const int tid = threadIdx.x, lane = tid & 63;
  const int wm = tid >> 7, wo = (tid >> 6) & 1;
  const long bm = blockIdx.x, bo = blockIdx.y;

  f32x4 acc[2][4] = {};
  const char* Ab = (const char*)(A + bm * 64 * 256);
  const char* Wb = (const char*)(W + bo * 128 * 256);
  for (int kt = 0; kt < 8; ++kt) {
    {
      const int fb = tid * 16;
      gload_lds16(Ab + (long)(fb >> 6) * 512 + kt * 64 + (fb & 63), lds + fb);
    }
#pragma unroll
    for (int c = 0; c < 2; ++c) {
      const int fb = c * 4096 + tid * 16;
      gload_lds16(Wb + (long)(fb >> 6) * 512 + kt * 64 + (fb & 63), lds + 4096 + fb);
    }
    __syncthreads();
    bf16x8 af[2], bfr[4];
    const int kb = (lane >> 4) * 16;
#pragma unroll
    for (int i = 0; i < 2; ++i)
      af[i] = *(const bf16x8*)(lds + (wm * 32 + i * 16 + (lane & 15)) * 64 + kb);
#pragma unroll
    for (int j = 0; j < 4; ++j)
      bfr[j] = *(const bf16x8*)(lds + 4096 + (wo * 64 + j * 16 + (lane & 15)) * 64 + kb);
#pragma unroll
    for (int i = 0; i < 2; ++i)
#pragma unroll
      for (int j = 0; j < 4; ++j)
        acc[i][j] = __builtin_amdgcn_mfma_f32_16x16x32_bf16(af[i], bfr[j], acc[i][j], 0, 0, 0);
    __syncthreads();
  }
#pragma unroll
  for (int i = 0; i < 2; ++i) {
#pragma unroll
    for (int j = 0; j < 4; ++j) {
      const int colg = (int)bo * 128 + wo * 64 + j * 16 + (lane & 15);
      const float bvv = bias[colg];
#pragma unroll
      for (int r = 0; r < 4; ++r) {
        const long rowg = bm * 64 + wm * 32 + i * 16 + (lane >> 4) * 4 + r;
        const float v = acc[i][j][r] + bvv;
        outb[rowg * 512 + colg] = f2bf(v > 0.f ? v : 0.f);
      }
    }
  }
}

// ---------- GEMM + bias + residual + LayerNorm fused epilogue ----------
// BM=16, BN=256 (full row per block), grid (M/16). KT = K/32.
// OUT_BF16: write bf16, else f32. RES_BF16: residual dtype.
template <int KT, int OUT_BF16, int RES_BF16>
__global__ __launch_bounds__(256, 2) void gemm_ln(
    const unsigned short* __restrict__ A,   // M x K bf16
    const unsigned short* __restrict__ W,   // 256 x K bf16
    const float* __restrict__ bias,         // 256
    const float* __restrict__ resf,         // M x 256 f32 (RES_BF16=0)
    const unsigned short* __restrict__ resb,// M x 256 bf16 (RES_BF16=1)
    const float* __restrict__ g, const float* __restrict__ b,
    float* __restrict__ outf,
    unsigned short* __restrict__ outb) {
  __shared__ __attribute__((aligned(16))) char lds[1024 + 16384];  // A 1KB | B 16KB
  __shared__ float2 part[4][16];
  const int tid = threadIdx.x, lane = tid & 63;
  const int wo = tid >> 6;                   // 0..3: 64-col stripe per wave
  const long bm = blockIdx.x;
  constexpr int K = KT * 32;

  f32x4 acc[4] = {};
  const char* Ab = (const char*)(A + bm * 16 * (long)K);
  for (int kt = 0; kt < KT; ++kt) {
    if (tid < 64) {
      const int fb = tid * 16;
      gload_lds16(Ab + (long)(fb >> 6) * (K * 2) + kt * 64 + (fb & 63), lds + fb);
    }
#pragma unroll
    for (int c = 0; c < 4; ++c) {
      const int fb = c * 4096 + tid * 16;
      gload_lds16((const char*)W + (long)(fb >> 6) * (K * 2) + kt * 64 + (fb & 63), lds + 1024 + fb);
    }
    __syncthreads();
    bf16x8 af, bfr[4];
    const int kb = (lane >> 4) * 16;
    af = *(const bf16x8*)(lds + ((lane & 15)) * 64 + kb);
#pragma unroll
    for (int j = 0; j < 4; ++j)
      bfr[j] = *(const bf16x8*)(lds + 1024 + (wo * 64 + j * 16 + (lane & 15)) * 64 + kb);
#pragma unroll
    for (int j = 0; j < 4; ++j)
      acc[j] = __builtin_amdgcn_mfma_f32_16x16x32_bf16(af, bfr[j], acc[j], 0, 0, 0);
    __syncthreads();
  }

  // epilogue: v = acc + bias + res; LN over 256 cols per row (16 rows/block)
  float gj[4], bj[4], biasj[4];
  int colg[4];
#pragma unroll
  for (int j = 0; j < 4; ++j) {
    colg[j] = wo * 64 + j * 16 + (lane & 15);
    gj[j] = g[colg[j]]; bj[j] = b[colg[j]]; biasj[j] = bias[colg[j]];
  }
  float v[4][4];
#pragma unroll
  for (int r = 0; r < 4; ++r) {
    const int row_local = (lane >> 4) * 4 + r;
    const long rowg = bm * 16 + row_local;
    float s = 0.f, s2 = 0.f;
#pragma unroll
    for (int j = 0; j < 4; ++j) {
      const float rv = RES_BF16 ? bf2f(resb[rowg * 256 + colg[j]]) : resf[rowg * 256 + colg[j]];
      float vv = acc[j][r] + biasj[j] + rv;
      v[j][r] = vv;
      s += vv; s2 = fmaf(vv, vv, s2);
    }
#pragma unroll
    for (int m = 8; m > 0; m >>= 1) { s += __shfl_xor(s, m, 16); s2 += __shfl_xor(s2, m, 16); }
    if ((lane & 15) == 0) part[wo][row_local] = make_float2(s, s2);
  }
  __syncthreads();
#pragma unroll
  for (int r = 0; r < 4; ++r) {
    const int row_local = (lane >> 4) * 4 + r;
    const long rowg = bm * 16 + row_local;
    float s = 0.f, s2 = 0.f;
#pragma unroll
    for (int wq = 0; wq < 4; ++wq) { s += part[wq][row_local].x; s2 += part[wq][row_local].y; }
    const float mu = s * (1.f / 256.f);
    const float var = s2 * (1.f / 256.f) - mu * mu;
    const float inv = rsqrtf(var + 1e-5f);
#pragma unroll
    for (int j = 0; j < 4; ++j) {
      const float y = (v[j][r] - mu) * inv * gj[j] + bj[j];
      if (OUT_BF16) outb[rowg * 256 + colg[j]] = f2bf(y);
      else outf[rowg * 256 + colg[j]] = y;
    }
  }
}

// ---------- fused gather + RPE rotary + MHA, register-resident K/q ----------
__global__ __launch_bounds__(256, 4) void attn2(
    const unsigned short* __restrict__ qb,   // N x 256 (bf16)
    const unsigned short* __restrict__ kbp,  // M x 256 (bf16)
    const unsigned short* __restrict__ vbp,  // M x 256 (bf16)
    const int* __restrict__ idx,             // N x 32
    const float* __restrict__ icoord,        // N x 3
    const float* __restrict__ mcoord,        // M x 3
    const float* __restrict__ mask,          // N x 32
    const float4* __restrict__ rpe4,         // 128 x {w0,w1,w2,b}
    unsigned short* __restrict__ hb)         // N x 256 (bf16)
{
  __shared__ int idx_s[32];
  __shared__ float4 relm_s[32];
  __shared__ float4 rpe_s[128];
  __shared__ float p_s[256];
  __shared__ __attribute__((aligned(16))) unsigned short vls[32][256];

  const int n = blockIdx.x, t = threadIdx.x;
  if (t < 128) rpe_s[t] = rpe4[t];
  if (t < 32) {
    const int m = idx[n * 32 + t];
    idx_s[t] = m;
    float4 rm;
    rm.x = mcoord[(long)m * 3 + 0] - icoord[(long)n * 3 + 0];
    rm.y = mcoord[(long)m * 3 + 1] - icoord[(long)n * 3 + 1];
    rm.z = mcoord[(long)m * 3 + 2] - icoord[(long)n * 3 + 2];
    rm.w = mask[n * 32 + t];
    relm_s[t] = rm;
  }
  __syncthreads();

#pragma unroll
  for (int i = 0; i < 4; ++i) {
    const int b = i * 4096 + t * 16;
    const int r = b >> 9, cb = b & 511;
    gload_lds16((const char*)vbp + (long)idx_s[r] * 512 + cb, (char*)vls + b);
  }

  const int h = t >> 5, k = t & 31;
  const float4 rm = relm_s[k];
  const long krow = idx_s[k];

  u16x8 kv8[4], qv8[4];
  {
    const u16x8* kp = (const u16x8*)(kbp + krow * 256 + h * 32);
    const u16x8* qp = (const u16x8*)(qb + (long)n * 256 + h * 32);
#pragma unroll
    for (int i = 0; i < 4; ++i) { kv8[i] = kp[i]; qv8[i] = qp[i]; }
  }

  float sc = 0.f;
#pragma unroll
  for (int j2 = 0; j2 < 16; ++j2) {
    const float4 wj = rpe_s[h * 16 + j2];
    const float ang = fmaf(wj.x, rm.x, fmaf(wj.y, rm.y, fmaf(wj.z, rm.z, wj.w)));
    float sn, cs;
    __sincosf(ang, &sn, &cs);
    const int wi = j2 >> 2, e0 = (j2 & 3) * 2;
    const float x0 = bf2f(kv8[wi][e0]), x1 = bf2f(kv8[wi][e0 + 1]);
    const float q0 = bf2f(qv8[wi][e0]), q1 = bf2f(qv8[wi][e0 + 1]);
    const float k0 = fmaf(x0, cs, -x1 * sn);
    const float k1 = fmaf(x0, sn, x1 * cs);
    sc = fmaf(q0, k0, sc);
    sc = fmaf(q1, k1, sc);
  }
  sc = sc * 0.17677669529663687f - 1e6f * (1.f - rm.w);

  float mx = sc;
#pragma unroll
  for (int m = 16; m > 0; m >>= 1) mx = fmaxf(mx, __shfl_xor(mx, m, 32));
  const float e = __expf(sc - mx);
  float sum = e;
#pragma unroll
  for (int m = 16; m > 0; m >>= 1) sum += __shfl_xor(sum, m, 32);
  p_s[t] = e / sum;
  __syncthreads();

  float acc = 0.f;
#pragma unroll
  for (int k4 = 0; k4 < 8; ++k4) {
    const float4 p4 = *(const float4*)(p_s + (t >> 5) * 32 + k4 * 4);
    acc = fmaf(p4.x, bf2f(vls[k4 * 4 + 0][t]), acc);
    acc = fmaf(p4.y, bf2f(vls[k4 * 4 + 1][t]), acc);
    acc = fmaf(p4.z, bf2f(vls[k4 * 4 + 2][t]), acc);
    acc = fmaf(p4.w, bf2f(vls[k4 * 4 + 3][t]), acc);
  }
  hb[(long)n * 256 + t] = f2bf(acc);
}

// ---------- launch ----------
extern "C" void kernel_launch(void* const* d_in, const int* in_sizes, int n_in,
                              void* d_out, int out_size, void* d_ws, size_t ws_size,
                              hipStream_t stream) {
  const float* x    = (const float*)d_in[0];
  const float* mem  = (const float*)d_in[1];
  const int* idx    = (const int*)d_in[2];
  const float* ic   = (const float*)d_in[3];
  const float* mc   = (const float*)d_in[4];
  const float* mask = (const float*)d_in[5];
  const float* Wq = (const float*)d_in[6];  const float* bq = (const float*)d_in[7];
  const float* Wk = (const float*)d_in[8];  const float* bk = (const float*)d_in[9];
  const float* Wv = (const float*)d_in[10]; const float* bv = (const float*)d_in[11];
  const float* Wo = (const float*)d_in[12]; const float* bo = (const float*)d_in[13];
  const float* g1 = (const float*)d_in[14]; const float* b1 = (const float*)d_in[15];
  const float* Wrpe = (const float*)d_in[16]; const float* brpe = (const float*)d_in[17];
  const float* We = (const float*)d_in[18]; const float* be = (const float*)d_in[19];
  const float* Ws = (const float*)d_in[20]; const float* bs = (const float*)d_in[21];
  const float* g2 = (const float*)d_in[22]; const float* b2 = (const float*)d_in[23];

  char* w = (char*)d_ws;
  const size_t MB = 1ull << 20;
  unsigned short* kbp   = (unsigned short*)(w + 0);        // 4MB
  unsigned short* vbp   = (unsigned short*)(w + 4 * MB);   // 4MB
  unsigned short* qbuf  = (unsigned short*)(w + 8 * MB);   // 4MB
  unsigned short* hb    = (unsigned short*)(w + 12 * MB);  // 4MB
  unsigned short* out1b = (unsigned short*)(w + 16 * MB);  // 4MB
  unsigned short* ffb   = (unsigned short*)(w + 20 * MB);  // 8MB (8192x512 bf16)
  unsigned short* wob  = (unsigned short*)(w + 28 * MB);   // 128KB
  unsigned short* web  = wob + 65536;                      // 256KB
  unsigned short* wsb  = web + 131072;                     // 256KB
  float4*         rpe4 = (float4*)(wsb + 131072);          // 2KB

  // fused q/k/v projections + weight conversions (one launch)
  gemm_proj<<<dim3(128, 7), 256, 0, stream>>>(
      x, mem, Wq, Wk, Wv, Wo, We, Ws, Wrpe, brpe, bq, bk, bv,
      qbuf, kbp, vbp, wob, web, wsb, rpe4);

  // fused gather + rotary + attention
  attn2<<<8192, 256, 0, stream>>>(qbuf, kbp, vbp, idx, ic, mc, mask, rpe4, hb);

  // output proj + residual(x, f32) + LN1 -> bf16 only
  gemm_ln<8, 1, 0><<<512, 256, 0, stream>>>(
      hb, wob, bo, x, nullptr, g1, b1, nullptr, out1b);

  // FFN1 (relu)
  gemm_relu<<<dim3(128, 4), 256, 0, stream>>>(out1b, web, be, ffb);

  // FFN2 + residual(out1b, bf16) + LN2 -> d_out (f32)
  gemm_ln<16, 0, 1><<<512, 256, 0, stream>>>(
      ffb, wsb, bs, nullptr, out1b, g2, b2, (float*)d_out, nullptr);
}